// Round 4
// baseline (186.297 us; speedup 1.0000x reference)
//
#include <hip/hip_runtime.h>
#include <hip/hip_bf16.h>
#include <math.h>

#define N 512
#define D 128
#define DD (D*D)
#define ND (N*D)
#define LSTR 132   // LDS row stride (floats) for 128-wide tiles
#define CSTR 36    // LDS row stride for 32-wide c tile

__device__ __forceinline__ float sigmoidf_(float x) { return 1.f / (1.f + expf(-x)); }

// ---------------- transpose W_mem layers 1..3 for backward ----------------
__global__ void k_transpose(const float* __restrict__ W_mem, float* __restrict__ WT) {
    int idx = blockIdx.x * 256 + threadIdx.x;
    int l = idx / DD;
    int r = idx % DD;
    int i = r / D;
    int j = r % D;
    WT[idx] = W_mem[(l + 1) * DD + j * D + i];
}

// ---------------- phase 1: per-token scalars, k/v/q, MLP fwd+bwd ----------------
__global__ __launch_bounds__(512) void k_phase1(
    const float* __restrict__ seq, const float* __restrict__ W_mem,
    const float* __restrict__ W_q, const float* __restrict__ W_kv,
    const float* __restrict__ W_mom, const float* __restrict__ W_step,
    const float* __restrict__ W_decay, const float* __restrict__ WT,
    float* __restrict__ Q, float* __restrict__ INS, float* __restrict__ ES,
    float* __restrict__ am, float* __restrict__ dec)
{
    __shared__ float s_seq[D], s_v[D], s_cur[D];
    __shared__ float s_h[4][D];
    __shared__ float s_part[4][D];
    __shared__ float s_p3[4][3][D];
    __shared__ float s_red[8];
    __shared__ float s_lr;

    const int t = blockIdx.x;
    const int tid = threadIdx.x;
    const int j = tid & 127;
    const int p = tid >> 7;
    const int i0 = p * 32;

    if (p == 0) s_seq[j] = seq[t * D + j];
    __syncthreads();

    float ps = 0.f;
    if (p == 1) ps = s_seq[j] * W_step[j];
    else if (p == 2) ps = s_seq[j] * W_mom[j];
    else if (p == 3) ps = s_seq[j] * W_decay[j];
#pragma unroll
    for (int off = 32; off > 0; off >>= 1) ps += __shfl_down(ps, off);
    if ((tid & 63) == 0) s_red[tid >> 6] = ps;
    __syncthreads();
    if (tid == 0) s_lr = s_red[2] + s_red[3];
    else if (tid == 1) am[t] = s_red[4] + s_red[5];
    else if (tid == 2) dec[t] = 1.f - sigmoidf_(s_red[6] + s_red[7]);

    float kp = 0.f, vp = 0.f, qp = 0.f;
#pragma unroll 8
    for (int ii = 0; ii < 32; ii++) {
        int i = i0 + ii;
        float si = s_seq[i];
        kp += si * W_kv[i * 256 + j];
        vp += si * W_kv[i * 256 + 128 + j];
        qp += si * W_q[i * 128 + j];
    }
    s_p3[p][0][j] = kp; s_p3[p][1][j] = vp; s_p3[p][2][j] = qp;
    __syncthreads();
    if (p == 0) {
        float kj = s_p3[0][0][j] + s_p3[1][0][j] + s_p3[2][0][j] + s_p3[3][0][j];
        s_cur[j] = kj;
        INS[t * D + j] = kj;
    } else if (p == 1) {
        s_v[j] = s_p3[0][1][j] + s_p3[1][1][j] + s_p3[2][1][j] + s_p3[3][1][j];
    } else if (p == 2) {
        Q[t * D + j] = s_p3[0][2][j] + s_p3[1][2][j] + s_p3[2][2][j] + s_p3[3][2][j];
    }
    __syncthreads();

    for (int l = 0; l < 4; l++) {
        const float* Wl = W_mem + l * DD;
        float yp = 0.f;
#pragma unroll 8
        for (int ii = 0; ii < 32; ii++) {
            int i = i0 + ii;
            yp += s_cur[i] * Wl[i * D + j];
        }
        s_part[p][j] = yp;
        __syncthreads();
        if (p == 0) {
            float y = s_part[0][j] + s_part[1][j] + s_part[2][j] + s_part[3][j];
            s_h[l][j] = y;
            if (l < 3) {
                float a = y * sigmoidf_(y);
                s_cur[j] = a;
                INS[(l + 1) * ND + t * D + j] = a;
            }
        }
        __syncthreads();
    }

    if (p == 0) {
        float e = -s_lr * (2.f / (float)D) * (s_h[3][j] - s_v[j]);
        ES[3 * ND + t * D + j] = e;
        s_cur[j] = e;
    }
    __syncthreads();

    for (int l = 3; l >= 1; l--) {
        const float* Wt = WT + (l - 1) * DD;
        float gp = 0.f;
#pragma unroll 8
        for (int ii = 0; ii < 32; ii++) {
            int i = i0 + ii;
            gp += s_cur[i] * Wt[i * D + j];
        }
        s_part[p][j] = gp;
        __syncthreads();
        if (p == 0) {
            float g = s_part[0][j] + s_part[1][j] + s_part[2][j] + s_part[3][j];
            float h = s_h[l - 1][j];
            float sg = sigmoidf_(h);
            float e2 = g * (sg * (1.f + h * (1.f - sg)));
            ES[(l - 1) * ND + t * D + j] = e2;
            s_cur[j] = e2;
        }
        __syncthreads();
    }
}

// ---------------- phase 2a: log-space prefix scans ----------------
__global__ __launch_bounds__(512) void k_logscan(
    const float* __restrict__ am, const float* __restrict__ dec,
    double* __restrict__ LA, double* __restrict__ LDp, int* __restrict__ NC)
{
    __shared__ double sa[N], sd[N];
    __shared__ int sn[N];
    const int t = threadIdx.x;
    float a = am[t];
    float d = dec[t];
    sa[t] = log((double)fmaxf(fabsf(a), 1e-38f));
    sd[t] = log((double)fmaxf(d, 1e-38f));
    sn[t] = (a < 0.f) ? 1 : 0;
    __syncthreads();
    for (int off = 1; off < N; off <<= 1) {
        double va = 0.0, vd = 0.0; int vn = 0;
        if (t >= off) { va = sa[t - off]; vd = sd[t - off]; vn = sn[t - off]; }
        __syncthreads();
        sa[t] += va; sd[t] += vd; sn[t] += vn;
        __syncthreads();
    }
    LA[t] = sa[t]; LDp[t] = sd[t]; NC[t] = sn[t];
}

// ---------------- phase 2b: build L_A, L_D ----------------
__global__ __launch_bounds__(256) void k_build(
    const double* __restrict__ LA, const double* __restrict__ LDp,
    const int* __restrict__ NC,
    float* __restrict__ Amat, float* __restrict__ Dmat)
{
    int idx = blockIdx.x * 256 + threadIdx.x;
    int u = idx >> 9;
    int s = idx & (N - 1);
    float va = 0.f, vd = 0.f;
    if (s <= u) {
        va = expf((float)(LA[u] - LA[s]));
        if ((NC[u] - NC[s]) & 1) va = -va;
        vd = expf((float)(LDp[u] - LDp[s]));
    }
    Amat[idx] = va;
    Dmat[idx] = vd;
}

// ---------------- phase 2c: beta = L_D @ L_A, split-K x4 + atomicAdd ----------------
__global__ __launch_bounds__(256) void k_betamm(
    const float* __restrict__ Dmat, const float* __restrict__ Amat,
    float* __restrict__ beta)
{
    const int bs = blockIdx.x;
    const int bt = blockIdx.y;
    const int z  = blockIdx.z;
    if (bs > bt) return;
    const int span = bt - bs + 1;
    const int chunk = (span + 3) >> 2;
    const int kBeg = bs + z * chunk;
    const int kEnd = (kBeg + chunk < bt + 1) ? (kBeg + chunk) : (bt + 1);
    if (kBeg >= kEnd) return;

    __shared__ float sD[32][33];
    __shared__ float sA[32][33];

    const int tx = threadIdx.x & 31;
    const int ty = threadIdx.x >> 5;
    float acc[4] = {0.f, 0.f, 0.f, 0.f};

    for (int kt = kBeg; kt < kEnd; kt++) {
        for (int i = threadIdx.x; i < 1024; i += 256) {
            int r = i >> 5, c = i & 31;
            sD[r][c] = Dmat[(bt * 32 + r) * N + kt * 32 + c];
            sA[r][c] = Amat[(kt * 32 + r) * N + bs * 32 + c];
        }
        __syncthreads();
#pragma unroll 8
        for (int k = 0; k < 32; k++) {
            float a = sA[k][tx];
#pragma unroll
            for (int j = 0; j < 4; j++)
                acc[j] += sD[ty + 8 * j][k] * a;
        }
        __syncthreads();
    }
#pragma unroll
    for (int j = 0; j < 4; j++)
        atomicAdd(&beta[(bt * 32 + ty + 8 * j) * N + bs * 32 + tx], acc[j]);
}

// ---------------- phase 3: one retrieval layer, tiled GEMM, split-s atomics ----
// grid (32, 19), block 64. z in 0..16: s-tile blocks (active if z <= r/2);
// z in 17..18: X@W k-half blocks. Y accumulated via atomicAdd (pre-zeroed).
__global__ __launch_bounds__(64) void k_layer(
    const float* __restrict__ Xin, float* __restrict__ Yout,
    const float* __restrict__ Wl, const float* __restrict__ INSl,
    const float* __restrict__ ESl, const float* __restrict__ beta,
    int actIn)
{
    const int r = blockIdx.x;
    const int z = blockIdx.y;
    const int t0 = r * 16;
    const int lane = threadIdx.x;
    const bool isW = (z >= 17);
    if (!isW && z > (r >> 1)) return;

    __shared__ float sX[16 * LSTR];
    __shared__ float sI[32 * LSTR];
    __shared__ float sE[32 * LSTR];
    __shared__ float sc[16 * CSTR];

    // ---- load X tile (16 x 128), silu on load if actIn ----
#pragma unroll
    for (int i = 0; i < 8; i++) {
        int f4 = lane + 64 * i;            // 0..511
        int row = f4 >> 5, c4 = f4 & 31;
        float4 v = ((const float4*)(Xin + t0 * D))[f4];
        if (actIn) {
            v.x = v.x * sigmoidf_(v.x); v.y = v.y * sigmoidf_(v.y);
            v.z = v.z * sigmoidf_(v.z); v.w = v.w * sigmoidf_(v.w);
        }
        *(float4*)(sX + row * LSTR + c4 * 4) = v;
    }

    if (isW) {
        __syncthreads();
        const int k0 = (z - 17) * 64;
        const int ti0 = (lane >> 4) * 4;
        const int jA = (lane & 15) * 4;
        float acc[4][8];
#pragma unroll
        for (int a = 0; a < 4; a++)
#pragma unroll
            for (int b = 0; b < 8; b++) acc[a][b] = 0.f;

#pragma unroll 4
        for (int k = k0; k < k0 + 64; k++) {
            float4 w0 = *(const float4*)(Wl + k * D + jA);
            float4 w1 = *(const float4*)(Wl + k * D + 64 + jA);
            float xv[4];
#pragma unroll
            for (int a = 0; a < 4; a++) xv[a] = sX[(ti0 + a) * LSTR + k];
#pragma unroll
            for (int a = 0; a < 4; a++) {
                acc[a][0] += xv[a] * w0.x; acc[a][1] += xv[a] * w0.y;
                acc[a][2] += xv[a] * w0.z; acc[a][3] += xv[a] * w0.w;
                acc[a][4] += xv[a] * w1.x; acc[a][5] += xv[a] * w1.y;
                acc[a][6] += xv[a] * w1.z; acc[a][7] += xv[a] * w1.w;
            }
        }
#pragma unroll
        for (int a = 0; a < 4; a++) {
            float* yp = Yout + (t0 + ti0 + a) * D;
#pragma unroll
            for (int q = 0; q < 4; q++) {
                atomicAdd(yp + jA + q,      acc[a][q]);
                atomicAdd(yp + 64 + jA + q, acc[a][4 + q]);
            }
        }
        return;
    }

    // ---- load INS/ES s-tiles (32 x 128 each) ----
    const int s0 = z * 32;
#pragma unroll
    for (int i = 0; i < 16; i++) {
        int f4 = lane + 64 * i;            // 0..1023
        int row = f4 >> 5, c4 = f4 & 31;
        float4 a = ((const float4*)(INSl + s0 * D))[f4];
        float4 b = ((const float4*)(ESl + s0 * D))[f4];
        *(float4*)(sI + row * LSTR + c4 * 4) = a;
        *(float4*)(sE + row * LSTR + c4 * 4) = b;
    }
    __syncthreads();

    // ---- GEMM1: c[ti][si] = (X . INS_s) * beta ----
    const int tiA = (lane >> 3) * 2;
    const int siA = lane & 7;
    float g1[2][4];
#pragma unroll
    for (int v = 0; v < 2; v++)
#pragma unroll
        for (int u = 0; u < 4; u++) g1[v][u] = 0.f;

    for (int k4 = 0; k4 < D; k4 += 4) {
        float4 a0 = *(float4*)(sX + tiA * LSTR + k4);
        float4 a1 = *(float4*)(sX + (tiA + 1) * LSTR + k4);
#pragma unroll
        for (int u = 0; u < 4; u++) {
            float4 b = *(float4*)(sI + (siA + 8 * u) * LSTR + k4);
            g1[0][u] += a0.x * b.x + a0.y * b.y + a0.z * b.z + a0.w * b.w;
            g1[1][u] += a1.x * b.x + a1.y * b.y + a1.z * b.z + a1.w * b.w;
        }
    }
#pragma unroll
    for (int v = 0; v < 2; v++)
#pragma unroll
        for (int u = 0; u < 4; u++) {
            int ti = tiA + v, si = siA + 8 * u;
            sc[ti * CSTR + si] = g1[v][u] * beta[(t0 + ti) * N + s0 + si];
        }
    __syncthreads();

    // ---- GEMM2: Y[ti][j] += sum_s c[ti][s] * E[s][j] ----
    const int ti0 = (lane >> 4) * 4;
    const int jA = (lane & 15) * 4;
    float acc[4][8];
#pragma unroll
    for (int a = 0; a < 4; a++)
#pragma unroll
        for (int b = 0; b < 8; b++) acc[a][b] = 0.f;

    for (int s4 = 0; s4 < 32; s4 += 4) {
        float cva[4][4];
#pragma unroll
        for (int a = 0; a < 4; a++)
            *(float4*)cva[a] = *(float4*)(sc + (ti0 + a) * CSTR + s4);
#pragma unroll
        for (int u = 0; u < 4; u++) {
            float4 e0 = *(float4*)(sE + (s4 + u) * LSTR + jA);
            float4 e1 = *(float4*)(sE + (s4 + u) * LSTR + 64 + jA);
#pragma unroll
            for (int a = 0; a < 4; a++) {
                float cu = cva[a][u];
                acc[a][0] += cu * e0.x; acc[a][1] += cu * e0.y;
                acc[a][2] += cu * e0.z; acc[a][3] += cu * e0.w;
                acc[a][4] += cu * e1.x; acc[a][5] += cu * e1.y;
                acc[a][6] += cu * e1.z; acc[a][7] += cu * e1.w;
            }
        }
    }
#pragma unroll
    for (int a = 0; a < 4; a++) {
        float* yp = Yout + (t0 + ti0 + a) * D;
#pragma unroll
        for (int q = 0; q < 4; q++) {
            atomicAdd(yp + jA + q,      acc[a][q]);
            atomicAdd(yp + 64 + jA + q, acc[a][4 + q]);
        }
    }
}

extern "C" void kernel_launch(void* const* d_in, const int* in_sizes, int n_in,
                              void* d_out, int out_size, void* d_ws, size_t ws_size,
                              hipStream_t stream) {
    const float* seq     = (const float*)d_in[0];
    const float* W_mem   = (const float*)d_in[1];
    const float* W_q     = (const float*)d_in[2];
    const float* W_kv    = (const float*)d_in[3];
    const float* W_mom   = (const float*)d_in[4];
    const float* W_step  = (const float*)d_in[5];
    const float* W_decay = (const float*)d_in[6];
    float* out = (float*)d_out;

    float* ws   = (float*)d_ws;
    float* am   = ws;                  // N
    float* dec  = am + N;              // N
    float* Q    = dec + N;             // N*D
    float* INS  = Q + ND;              // 4*N*D
    float* ES   = INS + 4 * ND;        // 4*N*D
    float* beta = ES + 4 * ND;         // N*N
    float* Y012 = beta + N * N;        // 3*N*D   (layer outputs, pre-act)
    float* WT   = Y012 + 3 * ND;       // 3*D*D
    float* Amat = WT + 3 * DD;         // N*N
    float* Dmat = Amat + N * N;        // N*N
    double* LA  = (double*)(Dmat + N * N);
    double* LDp = LA + N;
    int* NC     = (int*)(LDp + N);

    // zero beta + Y buffers (contiguous) and out
    hipMemsetAsync(beta, 0, (N * N + 3 * ND) * sizeof(float), stream);
    hipMemsetAsync(out, 0, ND * sizeof(float), stream);

    k_transpose<<<192, 256, 0, stream>>>(W_mem, WT);
    k_phase1<<<N, 512, 0, stream>>>(seq, W_mem, W_q, W_kv, W_mom, W_step, W_decay,
                                    WT, Q, INS, ES, am, dec);
    k_logscan<<<1, N, 0, stream>>>(am, dec, LA, LDp, NC);
    k_build<<<(N * N) / 256, 256, 0, stream>>>(LA, LDp, NC, Amat, Dmat);
    dim3 mmgrid(N / 32, N / 32, 4);
    k_betamm<<<mmgrid, 256, 0, stream>>>(Dmat, Amat, beta);

    float* Y0 = Y012;
    float* Y1 = Y012 + ND;
    float* Y2 = Y012 + 2 * ND;
    dim3 lgrid(32, 19);
    k_layer<<<lgrid, 64, 0, stream>>>(Q,  Y0,  W_mem,          INS,          ES,          beta, 0);
    k_layer<<<lgrid, 64, 0, stream>>>(Y0, Y1,  W_mem + DD,     INS + ND,     ES + ND,     beta, 1);
    k_layer<<<lgrid, 64, 0, stream>>>(Y1, Y2,  W_mem + 2 * DD, INS + 2 * ND, ES + 2 * ND, beta, 1);
    k_layer<<<lgrid, 64, 0, stream>>>(Y2, out, W_mem + 3 * DD, INS + 3 * ND, ES + 3 * ND, beta, 1);
}